// Round 6
// baseline (167.723 us; speedup 1.0000x reference)
//
#include <hip/hip_runtime.h>
#include <math.h>

#define B_ 4
#define N_ 4096
#define K_ 16
#define NT 64                    // 64 tiles of 64 points per cloud
#define INF __builtin_huge_valf()
#define SLACK 1e-4f

__device__ __forceinline__ float dpp_shr1_f(float x) {
    return __int_as_float(__builtin_amdgcn_update_dpp(
        __float_as_int(x), __float_as_int(x), 0x111, 0xF, 0xF, false));
}
__device__ __forceinline__ int dpp_shr1_i(int x) {
    return __builtin_amdgcn_update_dpp(x, x, 0x111, 0xF, 0xF, false);
}
__device__ __forceinline__ float readlane_f(float x, int l) {
    return __int_as_float(__builtin_amdgcn_readlane(__float_as_int(x), l));
}
__device__ __forceinline__ float rflf(float x) {   // force to SGPR
    return __int_as_float(__builtin_amdgcn_readfirstlane(__float_as_int(x)));
}
#if __has_builtin(__builtin_amdgcn_inverse_ballot_w64)
#define LANEBIT(m, lane) __builtin_amdgcn_inverse_ballot_w64(m)
#else
#define LANEBIT(m, lane) ((((m) >> (lane)) & 1ull) != 0)
#endif

// pop ONE candidate from mask mi into sorted 16-list (lanes 0..15 asc)
#define POP1(mi, di, sdi, sii, tb)                                         \
    {   int src = __builtin_ctzll(mi); mi &= mi - 1;                       \
        float v = readlane_f(di, src);                                     \
        int  vi = (tb) + src;                                              \
        unsigned long long mg = __ballot(sdi > v);                         \
        float usd = dpp_shr1_f(sdi); int usi = dpp_shr1_i(sii);            \
        bool gt = LANEBIT(mg, lane);                                       \
        bool pg = LANEBIT(mg << 1, lane);                                  \
        sdi = gt ? (pg ? usd : v ) : sdi;                                  \
        sii = gt ? (pg ? usi : vi) : sii; }

__device__ __forceinline__ int spread4(int v) {    // 4 bits -> every 3rd pos
    return (v & 1) | ((v & 2) << 2) | ((v & 4) << 4) | ((v & 8) << 6);
}

// ---- Morton counting-sort each (set,b) cloud into float4(x,y,z,orig) ------
__global__ __launch_bounds__(1024) void morton_sort_kernel(
    const float* __restrict__ ori, const float* __restrict__ adv,
    float4* __restrict__ gs)
{
    __shared__ int hist[4096];
    __shared__ int wsum[1024];
    const int tid = threadIdx.x;
    const int set = blockIdx.x >> 2, b = blockIdx.x & 3;
    const float* src = (set ? adv : ori) + (size_t)b * (N_*3);
    float4* dst = gs + (size_t)blockIdx.x * N_;

    #pragma unroll
    for (int k = 0; k < 4; ++k) hist[k*1024 + tid] = 0;
    __syncthreads();

    float px[4], py[4], pz[4]; int code[4];
    #pragma unroll
    for (int k = 0; k < 4; ++k) {
        int j = k*1024 + tid;
        float x = src[3*j+0], y = src[3*j+1], z = src[3*j+2];
        px[k] = x; py[k] = y; pz[k] = z;
        int ix = (int)((x + 4.25f) * (16.0f/8.5f));
        int iy = (int)((y + 4.25f) * (16.0f/8.5f));
        int iz = (int)((z + 4.25f) * (16.0f/8.5f));
        ix = ix < 0 ? 0 : (ix > 15 ? 15 : ix);
        iy = iy < 0 ? 0 : (iy > 15 ? 15 : iy);
        iz = iz < 0 ? 0 : (iz > 15 ? 15 : iz);
        code[k] = (spread4(ix) << 2) | (spread4(iy) << 1) | spread4(iz);
        atomicAdd(&hist[code[k]], 1);
    }
    __syncthreads();
    const int h0 = hist[4*tid], h1 = hist[4*tid+1],
              h2 = hist[4*tid+2], h3 = hist[4*tid+3];
    const int s = h0 + h1 + h2 + h3;
    wsum[tid] = s;
    __syncthreads();
    for (int st = 1; st < 1024; st <<= 1) {        // Hillis-Steele inclusive
        int tmp = (tid >= st) ? wsum[tid - st] : 0;
        __syncthreads();
        wsum[tid] += tmp;
        __syncthreads();
    }
    int eb = wsum[tid] - s;                        // exclusive base
    hist[4*tid]   = eb;
    hist[4*tid+1] = eb + h0;
    hist[4*tid+2] = eb + h0 + h1;
    hist[4*tid+3] = eb + h0 + h1 + h2;
    __syncthreads();
    #pragma unroll
    for (int k = 0; k < 4; ++k) {
        int j = k*1024 + tid;
        int pos = atomicAdd(&hist[code[k]], 1);
        dst[pos] = make_float4(px[k], py[k], pz[k], __int_as_float(j));
    }
}

// stage cloud -> LDS + per-tile AABBs (1024-thread block, 16 waves)
#define STAGE_AABB(gsrc)                                                   \
    _Pragma("unroll")                                                      \
    for (int k = 0; k < 4; ++k) {                                          \
        int j = k*1024 + tid;                                              \
        float4 f = (gsrc)[j];                                              \
        sxy[j] = make_float2(f.x, f.y);                                    \
        szs[j] = f.z;                                                      \
    }                                                                      \
    __syncthreads();                                                       \
    _Pragma("unroll")                                                      \
    for (int i = 0; i < 4; ++i) {                                          \
        int t = w*4 + i;                                                   \
        float2 pxy = sxy[t*64 + lane]; float pzz = szs[t*64 + lane];       \
        float x0 = pxy.x, x1 = pxy.x, y0 = pxy.y, y1 = pxy.y;              \
        float z0 = pzz, z1 = pzz;                                          \
        _Pragma("unroll")                                                  \
        for (int s2 = 1; s2 < 64; s2 <<= 1) {                              \
            x0 = fminf(x0, __shfl_xor(x0, s2));                            \
            x1 = fmaxf(x1, __shfl_xor(x1, s2));                            \
            y0 = fminf(y0, __shfl_xor(y0, s2));                            \
            y1 = fmaxf(y1, __shfl_xor(y1, s2));                            \
            z0 = fminf(z0, __shfl_xor(z0, s2));                            \
            z1 = fmaxf(z1, __shfl_xor(z1, s2));                            \
        }                                                                  \
        if (lane == 0) { alx[t]=x0; ahx[t]=x1; aly[t]=y0; ahy[t]=y1;       \
                         alz[t]=z0; ahz[t]=z1; }                           \
    }                                                                      \
    __syncthreads();

// AABB-to-point squared distance for THIS lane's tile (uses v_max3 idiom)
#define AABB2(qx,qy,qz)                                                    \
    ({ float dx_ = fmaxf(fmaxf(t_lx - (qx), (qx) - t_hx), 0.f);            \
       float dy_ = fmaxf(fmaxf(t_ly - (qy), (qy) - t_hy), 0.f);            \
       float dz_ = fmaxf(fmaxf(t_lz - (qz), (qz) - t_hz), 0.f);            \
       fmaf(dz_, dz_, fmaf(dy_, dy_, dx_*dx_)); })

// ---------------- argmin(adv -> ori): 1-NN per adv point ---------------------
__global__ __launch_bounds__(1024, 4) void curv_argmin_kernel(
    const float4* __restrict__ gs, int* __restrict__ nnidx)
{
    __shared__ float2 sxy[N_];
    __shared__ float  szs[N_];
    __shared__ float alx[NT], ahx[NT], aly[NT], ahy[NT], alz[NT], ahz[NT];
    const int tid = threadIdx.x, lane = tid & 63, w = tid >> 6;
    const int b = blockIdx.x >> 6, m = blockIdx.x & 63;
    const float4* go = gs + (size_t)b * N_;
    const float4* ga = gs + (size_t)(4 + b) * N_;

    STAGE_AABB(go)

    const int sq0 = (w*64 + m) * 4;                // 4 adv queries (sorted)
    float4 f0 = ga[sq0+0], f1 = ga[sq0+1], f2 = ga[sq0+2], f3 = ga[sq0+3];
    const float q0x=rflf(f0.x), q0y=rflf(f0.y), q0z=rflf(f0.z);
    const float q1x=rflf(f1.x), q1y=rflf(f1.y), q1z=rflf(f1.z);
    const float q2x=rflf(f2.x), q2y=rflf(f2.y), q2z=rflf(f2.z);
    const float q3x=rflf(f3.x), q3y=rflf(f3.y), q3z=rflf(f3.z);
    const int n0 = __builtin_amdgcn_readfirstlane(__float_as_int(f0.w));
    const int n1 = __builtin_amdgcn_readfirstlane(__float_as_int(f1.w));
    const int n2 = __builtin_amdgcn_readfirstlane(__float_as_int(f2.w));
    const int n3 = __builtin_amdgcn_readfirstlane(__float_as_int(f3.w));
    const float m2x0=-2.f*q0x, m2y0=-2.f*q0y, m2z0=-2.f*q0z;
    const float m2x1=-2.f*q1x, m2y1=-2.f*q1y, m2z1=-2.f*q1z;
    const float m2x2=-2.f*q2x, m2y2=-2.f*q2y, m2z2=-2.f*q2z;
    const float m2x3=-2.f*q3x, m2y3=-2.f*q3y, m2z3=-2.f*q3z;
    const float qq0 = fmaf(q0z,q0z, fmaf(q0y,q0y, q0x*q0x));
    const float qq1 = fmaf(q1z,q1z, fmaf(q1y,q1y, q1x*q1x));
    const float qq2 = fmaf(q2z,q2z, fmaf(q2y,q2y, q2x*q2x));
    const float qq3 = fmaf(q3z,q3z, fmaf(q3y,q3y, q3x*q3x));

    const float t_lx = alx[lane], t_hx = ahx[lane];
    const float t_ly = aly[lane], t_hy = ahy[lane];
    const float t_lz = alz[lane], t_hz = ahz[lane];
    float ad0 = AABB2(q0x,q0y,q0z), ad1 = AABB2(q1x,q1y,q1z);
    float ad2 = AABB2(q2x,q2y,q2z), ad3 = AABB2(q3x,q3y,q3z);

    // seed tile per query: lane with min AABB distance
    float v0=ad0, v1=ad1, v2=ad2, v3=ad3; int l0=lane,l1=lane,l2=lane,l3=lane;
    #pragma unroll
    for (int s2 = 1; s2 < 64; s2 <<= 1) {
        { float ov=__shfl_xor(v0,s2); int ol=__shfl_xor(l0,s2);
          if (ov<v0 || (ov==v0 && ol<l0)) { v0=ov; l0=ol; } }
        { float ov=__shfl_xor(v1,s2); int ol=__shfl_xor(l1,s2);
          if (ov<v1 || (ov==v1 && ol<l1)) { v1=ov; l1=ol; } }
        { float ov=__shfl_xor(v2,s2); int ol=__shfl_xor(l2,s2);
          if (ov<v2 || (ov==v2 && ol<l2)) { v2=ov; l2=ol; } }
        { float ov=__shfl_xor(v3,s2); int ol=__shfl_xor(l3,s2);
          if (ov<v3 || (ov==v3 && ol<l3)) { v3=ov; l3=ol; } }
    }
    unsigned long long scanned =
        (1ull << __builtin_amdgcn_readfirstlane(l0)) |
        (1ull << __builtin_amdgcn_readfirstlane(l1)) |
        (1ull << __builtin_amdgcn_readfirstlane(l2)) |
        (1ull << __builtin_amdgcn_readfirstlane(l3));

    float dm0=INF,dm1=INF,dm2=INF,dm3=INF; int jm0=0,jm1=0,jm2=0,jm3=0;
#define ASCAN(t)                                                           \
    {   int j = (t)*64 + lane;                                             \
        float2 p = sxy[j]; float pz2 = szs[j];                             \
        float pp = fmaf(pz2,pz2, fmaf(p.y,p.y, p.x*p.x));                  \
        float r0 = fmaf(pz2,m2z0, fmaf(p.y,m2y0, fmaf(p.x,m2x0, pp)));     \
        float r1 = fmaf(pz2,m2z1, fmaf(p.y,m2y1, fmaf(p.x,m2x1, pp)));     \
        float r2 = fmaf(pz2,m2z2, fmaf(p.y,m2y2, fmaf(p.x,m2x2, pp)));     \
        float r3 = fmaf(pz2,m2z3, fmaf(p.y,m2y3, fmaf(p.x,m2x3, pp)));     \
        if (r0 < dm0) { dm0 = r0; jm0 = j; }                               \
        if (r1 < dm1) { dm1 = r1; jm1 = j; }                               \
        if (r2 < dm2) { dm2 = r2; jm2 = j; }                               \
        if (r3 < dm3) { dm3 = r3; jm3 = j; }  }
    { unsigned long long cm = scanned;
      while (cm) { int t = __builtin_ctzll(cm); cm &= cm-1; ASCAN(t) } }

    // bound from seed scan, then remaining candidate tiles
    float bm0=dm0, bm1=dm1, bm2=dm2, bm3=dm3;
    #pragma unroll
    for (int s2 = 1; s2 < 64; s2 <<= 1) {
        bm0 = fminf(bm0, __shfl_xor(bm0, s2));
        bm1 = fminf(bm1, __shfl_xor(bm1, s2));
        bm2 = fminf(bm2, __shfl_xor(bm2, s2));
        bm3 = fminf(bm3, __shfl_xor(bm3, s2));
    }
    float bt0 = bm0 + qq0 + SLACK, bt1 = bm1 + qq1 + SLACK;
    float bt2 = bm2 + qq2 + SLACK, bt3 = bm3 + qq3 + SLACK;
    unsigned long long cm =
        ( __ballot(ad0 < bt0) | __ballot(ad1 < bt1)
        | __ballot(ad2 < bt2) | __ballot(ad3 < bt3) ) & ~scanned;
    while (cm) { int t = __builtin_ctzll(cm); cm &= cm-1; ASCAN(t) }
#undef ASCAN

    #pragma unroll
    for (int s2 = 1; s2 < 64; s2 <<= 1) {          // final lex (d, idx) min
        { float od=__shfl_xor(dm0,s2); int oj=__shfl_xor(jm0,s2);
          if (od<dm0 || (od==dm0 && oj<jm0)) { dm0=od; jm0=oj; } }
        { float od=__shfl_xor(dm1,s2); int oj=__shfl_xor(jm1,s2);
          if (od<dm1 || (od==dm1 && oj<jm1)) { dm1=od; jm1=oj; } }
        { float od=__shfl_xor(dm2,s2); int oj=__shfl_xor(jm2,s2);
          if (od<dm2 || (od==dm2 && oj<jm2)) { dm2=od; jm2=oj; } }
        { float od=__shfl_xor(dm3,s2); int oj=__shfl_xor(jm3,s2);
          if (od<dm3 || (od==dm3 && oj<jm3)) { dm3=od; jm3=oj; } }
    }
    if (lane == 0) {
        nnidx[b*N_ + n0] = __float_as_int(go[jm0].w);
        nnidx[b*N_ + n1] = __float_as_int(go[jm1].w);
        nnidx[b*N_ + n2] = __float_as_int(go[jm2].w);
        nnidx[b*N_ + n3] = __float_as_int(go[jm3].w);
    }
}

// ---------------- kappa for both sets, accumulate (sum, sumsq) ---------------
__global__ __launch_bounds__(1024, 8) void curv_kappa_kernel(
    const float4* __restrict__ gs, const float* __restrict__ nrm,
    const int* __restrict__ nnidx, double* __restrict__ acc)
{
    __shared__ float2 sxy[N_];
    __shared__ float  szs[N_];
    __shared__ float alx[NT], ahx[NT], aly[NT], ahy[NT], alz[NT], ahz[NT];
    __shared__ double rs[16], rss[16];
    const int tid = threadIdx.x, lane = tid & 63, w = tid >> 6;
    const int blk = blockIdx.x;
    const int job = blk >> 8;
    const int b   = (blk >> 6) & 3;
    const int m   = blk & 63;
    const float4* g  = gs + (size_t)(job*4 + b) * N_;
    const float* nb  = nrm + (size_t)b * (N_*3);

    STAGE_AABB(g)

    const int sq0 = (w*64 + m) * 4;                // 4 Morton-adjacent queries
    const int T0  = sq0 >> 6;
    float4 f0 = g[sq0+0], f1 = g[sq0+1], f2 = g[sq0+2], f3 = g[sq0+3];
    const float q0x=rflf(f0.x), q0y=rflf(f0.y), q0z=rflf(f0.z);
    const float q1x=rflf(f1.x), q1y=rflf(f1.y), q1z=rflf(f1.z);
    const float q2x=rflf(f2.x), q2y=rflf(f2.y), q2z=rflf(f2.z);
    const float q3x=rflf(f3.x), q3y=rflf(f3.y), q3z=rflf(f3.z);
    const int n0 = __builtin_amdgcn_readfirstlane(__float_as_int(f0.w));
    const int n1 = __builtin_amdgcn_readfirstlane(__float_as_int(f1.w));
    const int n2 = __builtin_amdgcn_readfirstlane(__float_as_int(f2.w));
    const int n3 = __builtin_amdgcn_readfirstlane(__float_as_int(f3.w));
    const int nn0 = job ? nnidx[b*N_ + n0] : n0;
    const int nn1 = job ? nnidx[b*N_ + n1] : n1;
    const int nn2 = job ? nnidx[b*N_ + n2] : n2;
    const int nn3 = job ? nnidx[b*N_ + n3] : n3;
    const float nx0=rflf(nb[3*nn0+0]), ny0=rflf(nb[3*nn0+1]), nz0=rflf(nb[3*nn0+2]);
    const float nx1=rflf(nb[3*nn1+0]), ny1=rflf(nb[3*nn1+1]), nz1=rflf(nb[3*nn1+2]);
    const float nx2=rflf(nb[3*nn2+0]), ny2=rflf(nb[3*nn2+1]), nz2=rflf(nb[3*nn2+2]);
    const float nx3=rflf(nb[3*nn3+0]), ny3=rflf(nb[3*nn3+1]), nz3=rflf(nb[3*nn3+2]);
    const float m2x0=-2.f*q0x, m2y0=-2.f*q0y, m2z0=-2.f*q0z;
    const float m2x1=-2.f*q1x, m2y1=-2.f*q1y, m2z1=-2.f*q1z;
    const float m2x2=-2.f*q2x, m2y2=-2.f*q2y, m2z2=-2.f*q2z;
    const float m2x3=-2.f*q3x, m2y3=-2.f*q3y, m2z3=-2.f*q3z;
    const float qq0 = fmaf(q0z,q0z, fmaf(q0y,q0y, q0x*q0x));
    const float qq1 = fmaf(q1z,q1z, fmaf(q1y,q1y, q1x*q1x));
    const float qq2 = fmaf(q2z,q2z, fmaf(q2y,q2y, q2x*q2x));
    const float qq3 = fmaf(q3z,q3z, fmaf(q3y,q3y, q3x*q3x));

    // AABB distances (lane = tile), live until mask build
    const float t_lx = alx[lane], t_hx = ahx[lane];
    const float t_ly = aly[lane], t_hy = ahy[lane];
    const float t_lz = alz[lane], t_hz = ahz[lane];
    float ad0 = AABB2(q0x,q0y,q0z), ad1 = AABB2(q1x,q1y,q1z);
    float ad2 = AABB2(q2x,q2y,q2z), ad3 = AABB2(q3x,q3y,q3z);

    // ---- seed: full bitonic sort of tile T0 for all 4 queries ----
    const int j0 = T0*64 + lane;
    float sd0, sd1, sd2, sd3;
    int   si0 = j0, si1 = j0, si2 = j0, si3 = j0;
    {
        float2 p = sxy[j0]; float pz0 = szs[j0];
        float pp = fmaf(pz0,pz0, fmaf(p.y,p.y, p.x*p.x));
        sd0 = fmaf(pz0,m2z0, fmaf(p.y,m2y0, fmaf(p.x,m2x0, pp)));
        sd1 = fmaf(pz0,m2z1, fmaf(p.y,m2y1, fmaf(p.x,m2x1, pp)));
        sd2 = fmaf(pz0,m2z2, fmaf(p.y,m2y2, fmaf(p.x,m2x2, pp)));
        sd3 = fmaf(pz0,m2z3, fmaf(p.y,m2y3, fmaf(p.x,m2x3, pp)));
        const int sl = sq0 & 63;
        if (lane == sl    ) sd0 = INF;             // exclude self
        if (lane == sl + 1) sd1 = INF;
        if (lane == sl + 2) sd2 = INF;
        if (lane == sl + 3) sd3 = INF;
    }
    #pragma unroll
    for (int k = 2; k <= 64; k <<= 1) {
        #pragma unroll
        for (int jj = k >> 1; jj > 0; jj >>= 1) {
            bool sel = ((lane & k) == 0) == ((lane & jj) == 0);
            { float o=__shfl_xor(sd0,jj); int a=__shfl_xor(si0,jj);
              if ((o<sd0)==sel) { sd0=o; si0=a; } }
            { float o=__shfl_xor(sd1,jj); int a=__shfl_xor(si1,jj);
              if ((o<sd1)==sel) { sd1=o; si1=a; } }
            { float o=__shfl_xor(sd2,jj); int a=__shfl_xor(si2,jj);
              if ((o<sd2)==sel) { sd2=o; si2=a; } }
            { float o=__shfl_xor(sd3,jj); int a=__shfl_xor(si3,jj);
              if ((o<sd3)==sel) { sd3=o; si3=a; } }
        }
    }
    float tau0 = readlane_f(sd0, 15), tau1 = readlane_f(sd1, 15);
    float tau2 = readlane_f(sd2, 15), tau3 = readlane_f(sd3, 15);

    // ---- candidate tiles: AABB within ball of (shifted) tau ----
    float tq0 = tau0 + qq0 + SLACK, tq1 = tau1 + qq1 + SLACK;
    float tq2 = tau2 + qq2 + SLACK, tq3 = tau3 + qq3 + SLACK;
    unsigned long long cm =
        ( __ballot(ad0 < tq0) | __ballot(ad1 < tq1)
        | __ballot(ad2 < tq2) | __ballot(ad3 < tq3) ) & ~(1ull << T0);

    while (cm) {
        int t = __builtin_ctzll(cm); cm &= cm - 1;
        int tb = t*64, j = tb + lane;
        float2 p = sxy[j]; float pz2 = szs[j];
        float pp = fmaf(pz2,pz2, fmaf(p.y,p.y, p.x*p.x));
        float d0 = fmaf(pz2,m2z0, fmaf(p.y,m2y0, fmaf(p.x,m2x0, pp)));
        float d1 = fmaf(pz2,m2z1, fmaf(p.y,m2y1, fmaf(p.x,m2x1, pp)));
        float d2 = fmaf(pz2,m2z2, fmaf(p.y,m2y2, fmaf(p.x,m2x2, pp)));
        float d3 = fmaf(pz2,m2z3, fmaf(p.y,m2y3, fmaf(p.x,m2x3, pp)));
        unsigned long long m0 = __ballot(d0 < tau0);
        unsigned long long m1 = __ballot(d1 < tau1);
        unsigned long long m2 = __ballot(d2 < tau2);
        unsigned long long m3 = __ballot(d3 < tau3);
        while (m0 | m1 | m2 | m3) {                // 4 independent chains: ILP
            if (m0) POP1(m0, d0, sd0, si0, tb)
            if (m1) POP1(m1, d1, sd1, si1, tb)
            if (m2) POP1(m2, d2, sd2, si2, tb)
            if (m3) POP1(m3, d3, sd3, si3, tb)
        }
        tau0 = readlane_f(sd0, 15); tau1 = readlane_f(sd1, 15);
        tau2 = readlane_f(sd2, 15); tau3 = readlane_f(sd3, 15);
    }

    // ---- kappa = mean_k |dot(normalize(nn - q), normal)| ----
    double ksum = 0.0, kss = 0.0;
#define KTAIL(siN, qxN, qyN, qzN, nxN, nyN, nzN)                           \
    {   float tl = 0.0f;                                                   \
        if (lane < K_) {                                                   \
            float2 p = sxy[siN]; float pz2 = szs[siN];                     \
            float vx = p.x - qxN, vy = p.y - qyN, vz = pz2 - qzN;          \
            float L  = sqrtf(vx*vx + vy*vy + vz*vz) + 1e-12f;              \
            tl = fabsf(fmaf(vz,nzN, fmaf(vy,nyN, vx*nxN))) / L;            \
        }                                                                  \
        tl += __shfl_xor(tl, 1); tl += __shfl_xor(tl, 2);                  \
        tl += __shfl_xor(tl, 4); tl += __shfl_xor(tl, 8);                  \
        if (lane == 0) { double kk = (double)tl * (1.0/16.0);              \
                         ksum += kk; kss += kk*kk; } }
    KTAIL(si0, q0x, q0y, q0z, nx0, ny0, nz0)
    KTAIL(si1, q1x, q1y, q1z, nx1, ny1, nz1)
    KTAIL(si2, q2x, q2y, q2z, nx2, ny2, nz2)
    KTAIL(si3, q3x, q3y, q3z, nx3, ny3, nz3)
#undef KTAIL

    if (lane == 0) { rs[w] = ksum; rss[w] = kss; }
    __syncthreads();
    if (tid == 0) {
        double s = 0.0, ss = 0.0;
        #pragma unroll
        for (int i = 0; i < 16; ++i) { s += rs[i]; ss += rss[i]; }
        int row = job*4 + b;
        atomicAdd(&acc[row*2+0], s);
        atomicAdd(&acc[row*2+1], ss);
    }
}

__global__ void curv_finalize_kernel(const double* __restrict__ acc,
                                     float* __restrict__ out)
{
    if (threadIdx.x == 0 && blockIdx.x == 0) {
        double st[8];
        #pragma unroll
        for (int r = 0; r < 8; ++r) {
            double s   = acc[2*r+0];
            double ss  = acc[2*r+1];
            double var = (ss - s*s / (double)N_) / (double)(N_ - 1);
            st[r] = var > 0.0 ? sqrt(var) : 0.0;
        }
        double o = 0.0;
        #pragma unroll
        for (int bb = 0; bb < 4; ++bb) o += fabs(st[4+bb] - st[bb]);
        out[0] = (float)(o * 0.25);
    }
}

extern "C" void kernel_launch(void* const* d_in, const int* in_sizes, int n_in,
                              void* d_out, int out_size, void* d_ws, size_t ws_size,
                              hipStream_t stream)
{
    const float* ori = (const float*)d_in[0];
    const float* adv = (const float*)d_in[1];
    const float* nrm = (const float*)d_in[2];
    double* acc   = (double*)d_ws;
    int*    nnidx = (int*)((char*)d_ws + 256);
    float4* gs    = (float4*)((char*)d_ws + 256 + 65536);
    float*  out   = (float*)d_out;

    hipMemsetAsync(acc, 0, 16 * sizeof(double), stream);
    morton_sort_kernel<<<8, 1024, 0, stream>>>(ori, adv, gs);
    curv_argmin_kernel<<<B_ * 64, 1024, 0, stream>>>(gs, nnidx);
    curv_kappa_kernel<<<2 * B_ * 64, 1024, 0, stream>>>(gs, nrm, nnidx, acc);
    curv_finalize_kernel<<<1, 64, 0, stream>>>(acc, out);
}

// Round 7
// 167.054 us; speedup vs baseline: 1.0040x; 1.0040x over previous
//
#include <hip/hip_runtime.h>
#include <math.h>

#define B_ 4
#define N_ 4096
#define K_ 16
#define NT 64                    // 64 tiles of 64 points per cloud
#define INF __builtin_huge_valf()
#define SLACK 1e-4f

__device__ __forceinline__ float dpp_shr1_f(float x) {
    return __int_as_float(__builtin_amdgcn_update_dpp(
        __float_as_int(x), __float_as_int(x), 0x111, 0xF, 0xF, false));
}
__device__ __forceinline__ int dpp_shr1_i(int x) {
    return __builtin_amdgcn_update_dpp(x, x, 0x111, 0xF, 0xF, false);
}
__device__ __forceinline__ float readlane_f(float x, int l) {
    return __int_as_float(__builtin_amdgcn_readlane(__float_as_int(x), l));
}
__device__ __forceinline__ float rflf(float x) {   // force to SGPR
    return __int_as_float(__builtin_amdgcn_readfirstlane(__float_as_int(x)));
}
#if __has_builtin(__builtin_amdgcn_inverse_ballot_w64)
#define LANEBIT(m, lane) __builtin_amdgcn_inverse_ballot_w64(m)
#else
#define LANEBIT(m, lane) ((((m) >> (lane)) & 1ull) != 0)
#endif

// pop ONE candidate from mask mi into sorted 16-list (lanes 0..15 asc)
#define POP1(mi, di, sdi, sii, tb)                                         \
    {   int src = __builtin_ctzll(mi); mi &= mi - 1;                       \
        float v = readlane_f(di, src);                                     \
        int  vi = (tb) + src;                                              \
        unsigned long long mg = __ballot(sdi > v);                         \
        float usd = dpp_shr1_f(sdi); int usi = dpp_shr1_i(sii);            \
        bool gt = LANEBIT(mg, lane);                                       \
        bool pg = LANEBIT(mg << 1, lane);                                  \
        sdi = gt ? (pg ? usd : v ) : sdi;                                  \
        sii = gt ? (pg ? usi : vi) : sii; }

__device__ __forceinline__ int spread4(int v) {    // 4 bits -> every 3rd pos
    return (v & 1) | ((v & 2) << 2) | ((v & 4) << 4) | ((v & 8) << 6);
}

// ---- Morton counting-sort each (set,b) cloud into float4(x,y,z,orig) ------
__global__ __launch_bounds__(1024) void morton_sort_kernel(
    const float* __restrict__ ori, const float* __restrict__ adv,
    float4* __restrict__ gs)
{
    __shared__ int hist[4096];
    __shared__ int wsum[1024];
    const int tid = threadIdx.x;
    const int set = blockIdx.x >> 2, b = blockIdx.x & 3;
    const float* src = (set ? adv : ori) + (size_t)b * (N_*3);
    float4* dst = gs + (size_t)blockIdx.x * N_;

    #pragma unroll
    for (int k = 0; k < 4; ++k) hist[k*1024 + tid] = 0;
    __syncthreads();

    float px[4], py[4], pz[4]; int code[4];
    #pragma unroll
    for (int k = 0; k < 4; ++k) {
        int j = k*1024 + tid;
        float x = src[3*j+0], y = src[3*j+1], z = src[3*j+2];
        px[k] = x; py[k] = y; pz[k] = z;
        int ix = (int)((x + 4.25f) * (16.0f/8.5f));
        int iy = (int)((y + 4.25f) * (16.0f/8.5f));
        int iz = (int)((z + 4.25f) * (16.0f/8.5f));
        ix = ix < 0 ? 0 : (ix > 15 ? 15 : ix);
        iy = iy < 0 ? 0 : (iy > 15 ? 15 : iy);
        iz = iz < 0 ? 0 : (iz > 15 ? 15 : iz);
        code[k] = (spread4(ix) << 2) | (spread4(iy) << 1) | spread4(iz);
        atomicAdd(&hist[code[k]], 1);
    }
    __syncthreads();
    const int h0 = hist[4*tid], h1 = hist[4*tid+1],
              h2 = hist[4*tid+2], h3 = hist[4*tid+3];
    const int s = h0 + h1 + h2 + h3;
    wsum[tid] = s;
    __syncthreads();
    for (int st = 1; st < 1024; st <<= 1) {        // Hillis-Steele inclusive
        int tmp = (tid >= st) ? wsum[tid - st] : 0;
        __syncthreads();
        wsum[tid] += tmp;
        __syncthreads();
    }
    int eb = wsum[tid] - s;                        // exclusive base
    hist[4*tid]   = eb;
    hist[4*tid+1] = eb + h0;
    hist[4*tid+2] = eb + h0 + h1;
    hist[4*tid+3] = eb + h0 + h1 + h2;
    __syncthreads();
    #pragma unroll
    for (int k = 0; k < 4; ++k) {
        int j = k*1024 + tid;
        int pos = atomicAdd(&hist[code[k]], 1);
        dst[pos] = make_float4(px[k], py[k], pz[k], __int_as_float(j));
    }
}

// stage cloud -> LDS + per-tile AABBs (1024-thread block, 16 waves)
#define STAGE_AABB(gsrc)                                                   \
    _Pragma("unroll")                                                      \
    for (int k = 0; k < 4; ++k) {                                          \
        int j = k*1024 + tid;                                              \
        float4 f = (gsrc)[j];                                              \
        sxy[j] = make_float2(f.x, f.y);                                    \
        szs[j] = f.z;                                                      \
    }                                                                      \
    __syncthreads();                                                       \
    _Pragma("unroll")                                                      \
    for (int i = 0; i < 4; ++i) {                                          \
        int t = w*4 + i;                                                   \
        float2 pxy = sxy[t*64 + lane]; float pzz = szs[t*64 + lane];       \
        float x0 = pxy.x, x1 = pxy.x, y0 = pxy.y, y1 = pxy.y;              \
        float z0 = pzz, z1 = pzz;                                          \
        _Pragma("unroll")                                                  \
        for (int s2 = 1; s2 < 64; s2 <<= 1) {                              \
            x0 = fminf(x0, __shfl_xor(x0, s2));                            \
            x1 = fmaxf(x1, __shfl_xor(x1, s2));                            \
            y0 = fminf(y0, __shfl_xor(y0, s2));                            \
            y1 = fmaxf(y1, __shfl_xor(y1, s2));                            \
            z0 = fminf(z0, __shfl_xor(z0, s2));                            \
            z1 = fmaxf(z1, __shfl_xor(z1, s2));                            \
        }                                                                  \
        if (lane == 0) { alx[t]=x0; ahx[t]=x1; aly[t]=y0; ahy[t]=y1;       \
                         alz[t]=z0; ahz[t]=z1; }                           \
    }                                                                      \
    __syncthreads();

// AABB-to-point squared distance for THIS lane's tile
#define AABB2(qx,qy,qz)                                                    \
    ({ float dx_ = fmaxf(fmaxf(t_lx - (qx), (qx) - t_hx), 0.f);            \
       float dy_ = fmaxf(fmaxf(t_ly - (qy), (qy) - t_hy), 0.f);            \
       float dz_ = fmaxf(fmaxf(t_lz - (qz), (qz) - t_hz), 0.f);            \
       fmaf(dz_, dz_, fmaf(dy_, dy_, dx_*dx_)); })

// wave argmin over (key, lane); result broadcast in kv/kl
#define WARGMIN(kv, kl)                                                    \
    _Pragma("unroll")                                                      \
    for (int s2 = 1; s2 < 64; s2 <<= 1) {                                  \
        float ov = __shfl_xor(kv, s2); int ol = __shfl_xor(kl, s2);        \
        if (ov < kv || (ov == kv && ol < kl)) { kv = ov; kl = ol; }        \
    }

// ---------------- argmin(adv -> ori): 1-NN per adv point ---------------------
__global__ __launch_bounds__(1024, 4) void curv_argmin_kernel(
    const float4* __restrict__ gs, int* __restrict__ nnidx)
{
    __shared__ float2 sxy[N_];
    __shared__ float  szs[N_];
    __shared__ float alx[NT], ahx[NT], aly[NT], ahy[NT], alz[NT], ahz[NT];
    const int tid = threadIdx.x, lane = tid & 63, w = tid >> 6;
    const int b = blockIdx.x >> 6, m = blockIdx.x & 63;
    const float4* go = gs + (size_t)b * N_;
    const float4* ga = gs + (size_t)(4 + b) * N_;

    STAGE_AABB(go)

    const int sq0 = (w*64 + m) * 4;                // 4 adv queries (sorted)
    float4 f0 = ga[sq0+0], f1 = ga[sq0+1], f2 = ga[sq0+2], f3 = ga[sq0+3];
    const float q0x=rflf(f0.x), q0y=rflf(f0.y), q0z=rflf(f0.z);
    const float q1x=rflf(f1.x), q1y=rflf(f1.y), q1z=rflf(f1.z);
    const float q2x=rflf(f2.x), q2y=rflf(f2.y), q2z=rflf(f2.z);
    const float q3x=rflf(f3.x), q3y=rflf(f3.y), q3z=rflf(f3.z);
    const int n0 = __builtin_amdgcn_readfirstlane(__float_as_int(f0.w));
    const int n1 = __builtin_amdgcn_readfirstlane(__float_as_int(f1.w));
    const int n2 = __builtin_amdgcn_readfirstlane(__float_as_int(f2.w));
    const int n3 = __builtin_amdgcn_readfirstlane(__float_as_int(f3.w));
    const float m2x0=-2.f*q0x, m2y0=-2.f*q0y, m2z0=-2.f*q0z;
    const float m2x1=-2.f*q1x, m2y1=-2.f*q1y, m2z1=-2.f*q1z;
    const float m2x2=-2.f*q2x, m2y2=-2.f*q2y, m2z2=-2.f*q2z;
    const float m2x3=-2.f*q3x, m2y3=-2.f*q3y, m2z3=-2.f*q3z;
    const float qq0 = fmaf(q0z,q0z, fmaf(q0y,q0y, q0x*q0x));
    const float qq1 = fmaf(q1z,q1z, fmaf(q1y,q1y, q1x*q1x));
    const float qq2 = fmaf(q2z,q2z, fmaf(q2y,q2y, q2x*q2x));
    const float qq3 = fmaf(q3z,q3z, fmaf(q3y,q3y, q3x*q3x));

    const float t_lx = alx[lane], t_hx = ahx[lane];
    const float t_ly = aly[lane], t_hy = ahy[lane];
    const float t_lz = alz[lane], t_hz = ahz[lane];
    const float ad0 = AABB2(q0x,q0y,q0z), ad1 = AABB2(q1x,q1y,q1z);
    const float ad2 = AABB2(q2x,q2y,q2z), ad3 = AABB2(q3x,q3y,q3z);

    float dm0=INF,dm1=INF,dm2=INF,dm3=INF; int jm0=0,jm1=0,jm2=0,jm3=0;
    float bm0=INF,bm1=INF,bm2=INF,bm3=INF;
    unsigned long long scanned = 0;

#define ASCAN(t)                                                           \
    {   int j = (t)*64 + lane;                                             \
        float2 p = sxy[j]; float pz2 = szs[j];                             \
        float pp = fmaf(pz2,pz2, fmaf(p.y,p.y, p.x*p.x));                  \
        float r0 = fmaf(pz2,m2z0, fmaf(p.y,m2y0, fmaf(p.x,m2x0, pp)));     \
        float r1 = fmaf(pz2,m2z1, fmaf(p.y,m2y1, fmaf(p.x,m2x1, pp)));     \
        float r2 = fmaf(pz2,m2z2, fmaf(p.y,m2y2, fmaf(p.x,m2x2, pp)));     \
        float r3 = fmaf(pz2,m2z3, fmaf(p.y,m2y3, fmaf(p.x,m2x3, pp)));     \
        if (r0 < dm0) { dm0 = r0; jm0 = j; }                               \
        if (r1 < dm1) { dm1 = r1; jm1 = j; }                               \
        if (r2 < dm2) { dm2 = r2; jm2 = j; }                               \
        if (r3 < dm3) { dm3 = r3; jm3 = j; }  }
#define BMRED()                                                            \
    {   bm0=dm0; bm1=dm1; bm2=dm2; bm3=dm3;                                \
        _Pragma("unroll")                                                  \
        for (int s2 = 1; s2 < 64; s2 <<= 1) {                              \
            bm0 = fminf(bm0, __shfl_xor(bm0, s2));                         \
            bm1 = fminf(bm1, __shfl_xor(bm1, s2));                         \
            bm2 = fminf(bm2, __shfl_xor(bm2, s2));                         \
            bm3 = fminf(bm3, __shfl_xor(bm3, s2));                         \
        } }

    // seed: scan the min-AABB tile of each query (usually 1-2 distinct)
    {
        float v0=ad0, v1=ad1, v2=ad2, v3=ad3;
        int l0=lane, l1=lane, l2=lane, l3=lane;
        WARGMIN(v0, l0) WARGMIN(v1, l1) WARGMIN(v2, l2) WARGMIN(v3, l3)
        scanned = (1ull << __builtin_amdgcn_readfirstlane(l0)) |
                  (1ull << __builtin_amdgcn_readfirstlane(l1)) |
                  (1ull << __builtin_amdgcn_readfirstlane(l2)) |
                  (1ull << __builtin_amdgcn_readfirstlane(l3));
        unsigned long long cm = scanned;
        while (cm) { int t = __builtin_ctzll(cm); cm &= cm-1; ASCAN(t) }
        BMRED()
    }

    // ordered + re-pruned: nearest unscanned tile still inside any ball
    for (;;) {
        float key = INF;
        if (!LANEBIT(scanned, lane)) {
            if (ad0 < bm0 + qq0 + SLACK) key = ad0;
            if (ad1 < bm1 + qq1 + SLACK) key = fminf(key, ad1);
            if (ad2 < bm2 + qq2 + SLACK) key = fminf(key, ad2);
            if (ad3 < bm3 + qq3 + SLACK) key = fminf(key, ad3);
        }
        float kv = key; int kl = lane;
        WARGMIN(kv, kl)
        if (kv == INF) break;
        int t = __builtin_amdgcn_readfirstlane(kl);
        scanned |= 1ull << t;
        ASCAN(t)
        BMRED()
    }
#undef ASCAN
#undef BMRED

    #pragma unroll
    for (int s2 = 1; s2 < 64; s2 <<= 1) {          // final lex (d, idx) min
        { float od=__shfl_xor(dm0,s2); int oj=__shfl_xor(jm0,s2);
          if (od<dm0 || (od==dm0 && oj<jm0)) { dm0=od; jm0=oj; } }
        { float od=__shfl_xor(dm1,s2); int oj=__shfl_xor(jm1,s2);
          if (od<dm1 || (od==dm1 && oj<jm1)) { dm1=od; jm1=oj; } }
        { float od=__shfl_xor(dm2,s2); int oj=__shfl_xor(jm2,s2);
          if (od<dm2 || (od==dm2 && oj<jm2)) { dm2=od; jm2=oj; } }
        { float od=__shfl_xor(dm3,s2); int oj=__shfl_xor(jm3,s2);
          if (od<dm3 || (od==dm3 && oj<jm3)) { dm3=od; jm3=oj; } }
    }
    if (lane == 0) {
        nnidx[b*N_ + n0] = __float_as_int(go[jm0].w);
        nnidx[b*N_ + n1] = __float_as_int(go[jm1].w);
        nnidx[b*N_ + n2] = __float_as_int(go[jm2].w);
        nnidx[b*N_ + n3] = __float_as_int(go[jm3].w);
    }
}

// ---------------- kappa for both sets, accumulate (sum, sumsq) ---------------
__global__ __launch_bounds__(1024, 8) void curv_kappa_kernel(
    const float4* __restrict__ gs, const float* __restrict__ nrm,
    const int* __restrict__ nnidx, double* __restrict__ acc)
{
    __shared__ float2 sxy[N_];
    __shared__ float  szs[N_];
    __shared__ float alx[NT], ahx[NT], aly[NT], ahy[NT], alz[NT], ahz[NT];
    __shared__ double rs[16], rss[16];
    const int tid = threadIdx.x, lane = tid & 63, w = tid >> 6;
    const int blk = blockIdx.x;
    const int job = blk >> 8;
    const int b   = (blk >> 6) & 3;
    const int m   = blk & 63;
    const float4* g  = gs + (size_t)(job*4 + b) * N_;
    const float* nb  = nrm + (size_t)b * (N_*3);

    STAGE_AABB(g)

    const int sq0 = (w*64 + m) * 4;                // 4 Morton-adjacent queries
    const int T0  = sq0 >> 6;
    float4 f0 = g[sq0+0], f1 = g[sq0+1], f2 = g[sq0+2], f3 = g[sq0+3];
    const float q0x=rflf(f0.x), q0y=rflf(f0.y), q0z=rflf(f0.z);
    const float q1x=rflf(f1.x), q1y=rflf(f1.y), q1z=rflf(f1.z);
    const float q2x=rflf(f2.x), q2y=rflf(f2.y), q2z=rflf(f2.z);
    const float q3x=rflf(f3.x), q3y=rflf(f3.y), q3z=rflf(f3.z);
    const int n0 = __builtin_amdgcn_readfirstlane(__float_as_int(f0.w));
    const int n1 = __builtin_amdgcn_readfirstlane(__float_as_int(f1.w));
    const int n2 = __builtin_amdgcn_readfirstlane(__float_as_int(f2.w));
    const int n3 = __builtin_amdgcn_readfirstlane(__float_as_int(f3.w));
    const int nn0 = job ? nnidx[b*N_ + n0] : n0;
    const int nn1 = job ? nnidx[b*N_ + n1] : n1;
    const int nn2 = job ? nnidx[b*N_ + n2] : n2;
    const int nn3 = job ? nnidx[b*N_ + n3] : n3;
    const float nx0=rflf(nb[3*nn0+0]), ny0=rflf(nb[3*nn0+1]), nz0=rflf(nb[3*nn0+2]);
    const float nx1=rflf(nb[3*nn1+0]), ny1=rflf(nb[3*nn1+1]), nz1=rflf(nb[3*nn1+2]);
    const float nx2=rflf(nb[3*nn2+0]), ny2=rflf(nb[3*nn2+1]), nz2=rflf(nb[3*nn2+2]);
    const float nx3=rflf(nb[3*nn3+0]), ny3=rflf(nb[3*nn3+1]), nz3=rflf(nb[3*nn3+2]);
    const float m2x0=-2.f*q0x, m2y0=-2.f*q0y, m2z0=-2.f*q0z;
    const float m2x1=-2.f*q1x, m2y1=-2.f*q1y, m2z1=-2.f*q1z;
    const float m2x2=-2.f*q2x, m2y2=-2.f*q2y, m2z2=-2.f*q2z;
    const float m2x3=-2.f*q3x, m2y3=-2.f*q3y, m2z3=-2.f*q3z;
    const float qq0 = fmaf(q0z,q0z, fmaf(q0y,q0y, q0x*q0x));
    const float qq1 = fmaf(q1z,q1z, fmaf(q1y,q1y, q1x*q1x));
    const float qq2 = fmaf(q2z,q2z, fmaf(q2y,q2y, q2x*q2x));
    const float qq3 = fmaf(q3z,q3z, fmaf(q3y,q3y, q3x*q3x));

    const float t_lx = alx[lane], t_hx = ahx[lane];
    const float t_ly = aly[lane], t_hy = ahy[lane];
    const float t_lz = alz[lane], t_hz = ahz[lane];
    const float ad0 = AABB2(q0x,q0y,q0z), ad1 = AABB2(q1x,q1y,q1z);
    const float ad2 = AABB2(q2x,q2y,q2z), ad3 = AABB2(q3x,q3y,q3z);

    // ---- seed: full bitonic sort of tile T0 for all 4 queries ----
    const int j0 = T0*64 + lane;
    float sd0, sd1, sd2, sd3;
    int   si0 = j0, si1 = j0, si2 = j0, si3 = j0;
    {
        float2 p = sxy[j0]; float pz0 = szs[j0];
        float pp = fmaf(pz0,pz0, fmaf(p.y,p.y, p.x*p.x));
        sd0 = fmaf(pz0,m2z0, fmaf(p.y,m2y0, fmaf(p.x,m2x0, pp)));
        sd1 = fmaf(pz0,m2z1, fmaf(p.y,m2y1, fmaf(p.x,m2x1, pp)));
        sd2 = fmaf(pz0,m2z2, fmaf(p.y,m2y2, fmaf(p.x,m2x2, pp)));
        sd3 = fmaf(pz0,m2z3, fmaf(p.y,m2y3, fmaf(p.x,m2x3, pp)));
        const int sl = sq0 & 63;
        if (lane == sl    ) sd0 = INF;             // exclude self
        if (lane == sl + 1) sd1 = INF;
        if (lane == sl + 2) sd2 = INF;
        if (lane == sl + 3) sd3 = INF;
    }
    #pragma unroll
    for (int k = 2; k <= 64; k <<= 1) {
        #pragma unroll
        for (int jj = k >> 1; jj > 0; jj >>= 1) {
            bool sel = ((lane & k) == 0) == ((lane & jj) == 0);
            { float o=__shfl_xor(sd0,jj); int a=__shfl_xor(si0,jj);
              if ((o<sd0)==sel) { sd0=o; si0=a; } }
            { float o=__shfl_xor(sd1,jj); int a=__shfl_xor(si1,jj);
              if ((o<sd1)==sel) { sd1=o; si1=a; } }
            { float o=__shfl_xor(sd2,jj); int a=__shfl_xor(si2,jj);
              if ((o<sd2)==sel) { sd2=o; si2=a; } }
            { float o=__shfl_xor(sd3,jj); int a=__shfl_xor(si3,jj);
              if ((o<sd3)==sel) { sd3=o; si3=a; } }
        }
    }
    float tau0 = readlane_f(sd0, 15), tau1 = readlane_f(sd1, 15);
    float tau2 = readlane_f(sd2, 15), tau3 = readlane_f(sd3, 15);

    // ---- ordered + re-pruned candidate-tile loop ----
    unsigned long long scanned = 1ull << T0;
    for (;;) {
        float key = INF;
        if (!LANEBIT(scanned, lane)) {
            if (ad0 < tau0 + qq0 + SLACK) key = ad0;
            if (ad1 < tau1 + qq1 + SLACK) key = fminf(key, ad1);
            if (ad2 < tau2 + qq2 + SLACK) key = fminf(key, ad2);
            if (ad3 < tau3 + qq3 + SLACK) key = fminf(key, ad3);
        }
        float kv = key; int kl = lane;
        WARGMIN(kv, kl)
        if (kv == INF) break;
        int t = __builtin_amdgcn_readfirstlane(kl);
        scanned |= 1ull << t;

        int tb = t*64, j = tb + lane;
        float2 p = sxy[j]; float pz2 = szs[j];
        float pp = fmaf(pz2,pz2, fmaf(p.y,p.y, p.x*p.x));
        float d0 = fmaf(pz2,m2z0, fmaf(p.y,m2y0, fmaf(p.x,m2x0, pp)));
        float d1 = fmaf(pz2,m2z1, fmaf(p.y,m2y1, fmaf(p.x,m2x1, pp)));
        float d2 = fmaf(pz2,m2z2, fmaf(p.y,m2y2, fmaf(p.x,m2x2, pp)));
        float d3 = fmaf(pz2,m2z3, fmaf(p.y,m2y3, fmaf(p.x,m2x3, pp)));
        unsigned long long m0 = __ballot(d0 < tau0);
        unsigned long long m1 = __ballot(d1 < tau1);
        unsigned long long m2 = __ballot(d2 < tau2);
        unsigned long long m3 = __ballot(d3 < tau3);
        while (m0 | m1 | m2 | m3) {                // 4 independent chains: ILP
            if (m0) POP1(m0, d0, sd0, si0, tb)
            if (m1) POP1(m1, d1, sd1, si1, tb)
            if (m2) POP1(m2, d2, sd2, si2, tb)
            if (m3) POP1(m3, d3, sd3, si3, tb)
        }
        tau0 = readlane_f(sd0, 15); tau1 = readlane_f(sd1, 15);
        tau2 = readlane_f(sd2, 15); tau3 = readlane_f(sd3, 15);
    }

    // ---- kappa = mean_k |dot(normalize(nn - q), normal)| ----
    double ksum = 0.0, kss = 0.0;
#define KTAIL(siN, qxN, qyN, qzN, nxN, nyN, nzN)                           \
    {   float tl = 0.0f;                                                   \
        if (lane < K_) {                                                   \
            float2 p2 = sxy[siN]; float pz3 = szs[siN];                    \
            float vx = p2.x - qxN, vy = p2.y - qyN, vz = pz3 - qzN;        \
            float L  = sqrtf(vx*vx + vy*vy + vz*vz) + 1e-12f;              \
            tl = fabsf(fmaf(vz,nzN, fmaf(vy,nyN, vx*nxN))) / L;            \
        }                                                                  \
        tl += __shfl_xor(tl, 1); tl += __shfl_xor(tl, 2);                  \
        tl += __shfl_xor(tl, 4); tl += __shfl_xor(tl, 8);                  \
        if (lane == 0) { double kk = (double)tl * (1.0/16.0);              \
                         ksum += kk; kss += kk*kk; } }
    KTAIL(si0, q0x, q0y, q0z, nx0, ny0, nz0)
    KTAIL(si1, q1x, q1y, q1z, nx1, ny1, nz1)
    KTAIL(si2, q2x, q2y, q2z, nx2, ny2, nz2)
    KTAIL(si3, q3x, q3y, q3z, nx3, ny3, nz3)
#undef KTAIL

    if (lane == 0) { rs[w] = ksum; rss[w] = kss; }
    __syncthreads();
    if (tid == 0) {
        double s = 0.0, ss = 0.0;
        #pragma unroll
        for (int i = 0; i < 16; ++i) { s += rs[i]; ss += rss[i]; }
        int row = job*4 + b;
        atomicAdd(&acc[row*2+0], s);
        atomicAdd(&acc[row*2+1], ss);
    }
}

__global__ void curv_finalize_kernel(const double* __restrict__ acc,
                                     float* __restrict__ out)
{
    if (threadIdx.x == 0 && blockIdx.x == 0) {
        double st[8];
        #pragma unroll
        for (int r = 0; r < 8; ++r) {
            double s   = acc[2*r+0];
            double ss  = acc[2*r+1];
            double var = (ss - s*s / (double)N_) / (double)(N_ - 1);
            st[r] = var > 0.0 ? sqrt(var) : 0.0;
        }
        double o = 0.0;
        #pragma unroll
        for (int bb = 0; bb < 4; ++bb) o += fabs(st[4+bb] - st[bb]);
        out[0] = (float)(o * 0.25);
    }
}

extern "C" void kernel_launch(void* const* d_in, const int* in_sizes, int n_in,
                              void* d_out, int out_size, void* d_ws, size_t ws_size,
                              hipStream_t stream)
{
    const float* ori = (const float*)d_in[0];
    const float* adv = (const float*)d_in[1];
    const float* nrm = (const float*)d_in[2];
    double* acc   = (double*)d_ws;
    int*    nnidx = (int*)((char*)d_ws + 256);
    float4* gs    = (float4*)((char*)d_ws + 256 + 65536);
    float*  out   = (float*)d_out;

    hipMemsetAsync(acc, 0, 16 * sizeof(double), stream);
    morton_sort_kernel<<<8, 1024, 0, stream>>>(ori, adv, gs);
    curv_argmin_kernel<<<B_ * 64, 1024, 0, stream>>>(gs, nnidx);
    curv_kappa_kernel<<<2 * B_ * 64, 1024, 0, stream>>>(gs, nrm, nnidx, acc);
    curv_finalize_kernel<<<1, 64, 0, stream>>>(acc, out);
}

// Round 8
// 163.496 us; speedup vs baseline: 1.0259x; 1.0218x over previous
//
#include <hip/hip_runtime.h>
#include <math.h>

#define B_ 4
#define N_ 4096
#define K_ 16
#define NT 64                    // 64 tiles of 64 points per cloud
#define INF __builtin_huge_valf()

__device__ __forceinline__ float dpp_shr1_f(float x) {
    return __int_as_float(__builtin_amdgcn_update_dpp(
        __float_as_int(x), __float_as_int(x), 0x111, 0xF, 0xF, false));
}
__device__ __forceinline__ int dpp_shr1_i(int x) {
    return __builtin_amdgcn_update_dpp(x, x, 0x111, 0xF, 0xF, false);
}
__device__ __forceinline__ float readlane_f(float x, int l) {
    return __int_as_float(__builtin_amdgcn_readlane(__float_as_int(x), l));
}
__device__ __forceinline__ float rflf(float x) {   // force to SGPR
    return __int_as_float(__builtin_amdgcn_readfirstlane(__float_as_int(x)));
}
#if __has_builtin(__builtin_amdgcn_inverse_ballot_w64)
#define LANEBIT(m, lane) __builtin_amdgcn_inverse_ballot_w64(m)
#else
#define LANEBIT(m, lane) ((((m) >> (lane)) & 1ull) != 0)
#endif

// pop ONE candidate from mask mi into sorted 16-list (lanes 0..15 asc)
#define POP1(mi, di, sdi, sii, tb)                                         \
    {   int src = __builtin_ctzll(mi); mi &= mi - 1;                       \
        float v = readlane_f(di, src);                                     \
        int  vi = (tb) + src;                                              \
        unsigned long long mg = __ballot(sdi > v);                         \
        float usd = dpp_shr1_f(sdi); int usi = dpp_shr1_i(sii);            \
        bool gt = LANEBIT(mg, lane);                                       \
        bool pg = LANEBIT(mg << 1, lane);                                  \
        sdi = gt ? (pg ? usd : v ) : sdi;                                  \
        sii = gt ? (pg ? usi : vi) : sii; }

__device__ __forceinline__ int spread4(int v) {    // 4 bits -> every 3rd pos
    return (v & 1) | ((v & 2) << 2) | ((v & 4) << 4) | ((v & 8) << 6);
}

// -- Morton counting-sort each (set,b) cloud: gs=(x,y,z,|p|^2), gidx=orig ----
__global__ __launch_bounds__(1024) void morton_sort_kernel(
    const float* __restrict__ ori, const float* __restrict__ adv,
    float4* __restrict__ gs, int* __restrict__ gidx)
{
    __shared__ int hist[4096];
    __shared__ int wsum[1024];
    const int tid = threadIdx.x;
    const int set = blockIdx.x >> 2, b = blockIdx.x & 3;
    const float* src = (set ? adv : ori) + (size_t)b * (N_*3);
    float4* dst = gs + (size_t)blockIdx.x * N_;
    int*    dsi = gidx + (size_t)blockIdx.x * N_;

    #pragma unroll
    for (int k = 0; k < 4; ++k) hist[k*1024 + tid] = 0;
    __syncthreads();

    float px[4], py[4], pz[4]; int code[4];
    #pragma unroll
    for (int k = 0; k < 4; ++k) {
        int j = k*1024 + tid;
        float x = src[3*j+0], y = src[3*j+1], z = src[3*j+2];
        px[k] = x; py[k] = y; pz[k] = z;
        int ix = (int)((x + 4.25f) * (16.0f/8.5f));
        int iy = (int)((y + 4.25f) * (16.0f/8.5f));
        int iz = (int)((z + 4.25f) * (16.0f/8.5f));
        ix = ix < 0 ? 0 : (ix > 15 ? 15 : ix);
        iy = iy < 0 ? 0 : (iy > 15 ? 15 : iy);
        iz = iz < 0 ? 0 : (iz > 15 ? 15 : iz);
        code[k] = (spread4(ix) << 2) | (spread4(iy) << 1) | spread4(iz);
        atomicAdd(&hist[code[k]], 1);
    }
    __syncthreads();
    const int h0 = hist[4*tid], h1 = hist[4*tid+1],
              h2 = hist[4*tid+2], h3 = hist[4*tid+3];
    const int s = h0 + h1 + h2 + h3;
    wsum[tid] = s;
    __syncthreads();
    for (int st = 1; st < 1024; st <<= 1) {        // Hillis-Steele inclusive
        int tmp = (tid >= st) ? wsum[tid - st] : 0;
        __syncthreads();
        wsum[tid] += tmp;
        __syncthreads();
    }
    int eb = wsum[tid] - s;                        // exclusive base
    hist[4*tid]   = eb;
    hist[4*tid+1] = eb + h0;
    hist[4*tid+2] = eb + h0 + h1;
    hist[4*tid+3] = eb + h0 + h1 + h2;
    __syncthreads();
    #pragma unroll
    for (int k = 0; k < 4; ++k) {
        int j = k*1024 + tid;
        int pos = atomicAdd(&hist[code[k]], 1);
        float pp = fmaf(pz[k],pz[k], fmaf(py[k],py[k], px[k]*px[k]));
        dst[pos] = make_float4(px[k], py[k], pz[k], pp);
        dsi[pos] = j;
    }
}

// ---------------- argmin(adv -> ori): 1-NN, brute 64-tile scan ---------------
__global__ __launch_bounds__(1024, 4) void curv_argmin_kernel(
    const float4* __restrict__ gs, const int* __restrict__ gidx,
    int* __restrict__ nnidx)
{
    __shared__ float4 sp[N_];
    const int tid = threadIdx.x, lane = tid & 63, w = tid >> 6;
    const int b = blockIdx.x >> 6, m = blockIdx.x & 63;
    const float4* go = gs + (size_t)b * N_;
    const int*    io = gidx + (size_t)b * N_;
    const float4* ga = gs + (size_t)(4 + b) * N_;
    const int*    ia = gidx + (size_t)(4 + b) * N_;

    #pragma unroll
    for (int k = 0; k < 4; ++k) { int j = k*1024 + tid; sp[j] = go[j]; }
    __syncthreads();

    const int sq0 = (w*64 + m) * 4;                // 4 adv queries (sorted)
    float4 f0 = ga[sq0+0], f1 = ga[sq0+1], f2 = ga[sq0+2], f3 = ga[sq0+3];
    const float m2x0=rflf(-2.f*f0.x), m2y0=rflf(-2.f*f0.y), m2z0=rflf(-2.f*f0.z);
    const float m2x1=rflf(-2.f*f1.x), m2y1=rflf(-2.f*f1.y), m2z1=rflf(-2.f*f1.z);
    const float m2x2=rflf(-2.f*f2.x), m2y2=rflf(-2.f*f2.y), m2z2=rflf(-2.f*f2.z);
    const float m2x3=rflf(-2.f*f3.x), m2y3=rflf(-2.f*f3.y), m2z3=rflf(-2.f*f3.z);

    float dm0=INF,dm1=INF,dm2=INF,dm3=INF; int jm0=0,jm1=0,jm2=0,jm3=0;
    for (int t = 0; t < NT; ++t) {
        int j = t*64 + lane;
        float4 p = sp[j];
        float r0 = fmaf(p.z,m2z0, fmaf(p.y,m2y0, fmaf(p.x,m2x0, p.w)));
        float r1 = fmaf(p.z,m2z1, fmaf(p.y,m2y1, fmaf(p.x,m2x1, p.w)));
        float r2 = fmaf(p.z,m2z2, fmaf(p.y,m2y2, fmaf(p.x,m2x2, p.w)));
        float r3 = fmaf(p.z,m2z3, fmaf(p.y,m2y3, fmaf(p.x,m2x3, p.w)));
        if (r0 < dm0) { dm0 = r0; jm0 = j; }       // strict: earliest sorted j
        if (r1 < dm1) { dm1 = r1; jm1 = j; }
        if (r2 < dm2) { dm2 = r2; jm2 = j; }
        if (r3 < dm3) { dm3 = r3; jm3 = j; }
    }
    #pragma unroll
    for (int s2 = 1; s2 < 64; s2 <<= 1) {          // final lex (r, idx) min
        { float od=__shfl_xor(dm0,s2); int oj=__shfl_xor(jm0,s2);
          if (od<dm0 || (od==dm0 && oj<jm0)) { dm0=od; jm0=oj; } }
        { float od=__shfl_xor(dm1,s2); int oj=__shfl_xor(jm1,s2);
          if (od<dm1 || (od==dm1 && oj<jm1)) { dm1=od; jm1=oj; } }
        { float od=__shfl_xor(dm2,s2); int oj=__shfl_xor(jm2,s2);
          if (od<dm2 || (od==dm2 && oj<jm2)) { dm2=od; jm2=oj; } }
        { float od=__shfl_xor(dm3,s2); int oj=__shfl_xor(jm3,s2);
          if (od<dm3 || (od==dm3 && oj<jm3)) { dm3=od; jm3=oj; } }
    }
    if (lane == 0) {
        nnidx[b*N_ + ia[sq0+0]] = io[jm0];
        nnidx[b*N_ + ia[sq0+1]] = io[jm1];
        nnidx[b*N_ + ia[sq0+2]] = io[jm2];
        nnidx[b*N_ + ia[sq0+3]] = io[jm3];
    }
}

// ---------------- kappa for both sets, accumulate (sum, sumsq) ---------------
__global__ __launch_bounds__(1024, 8) void curv_kappa_kernel(
    const float4* __restrict__ gs, const int* __restrict__ gidx,
    const float* __restrict__ nrm, const int* __restrict__ nnidx,
    double* __restrict__ acc)
{
    __shared__ float4 sp[N_];                      // (x,y,z,|p|^2)
    __shared__ double rs[16], rss[16];
    const int tid = threadIdx.x, lane = tid & 63, w = tid >> 6;
    const int blk = blockIdx.x;
    const int job = blk >> 8;
    const int b   = (blk >> 6) & 3;
    const int m   = blk & 63;
    const float4* g  = gs + (size_t)(job*4 + b) * N_;
    const int*    gi = gidx + (size_t)(job*4 + b) * N_;
    const float*  nb = nrm + (size_t)b * (N_*3);

    #pragma unroll
    for (int k = 0; k < 4; ++k) { int j = k*1024 + tid; sp[j] = g[j]; }
    __syncthreads();

    const int sq0 = (w*64 + m) * 4;                // 4 Morton-adjacent queries
    const int T0  = sq0 >> 6, sl = sq0 & 63;
    float4 f0 = sp[sq0+0], f1 = sp[sq0+1], f2 = sp[sq0+2], f3 = sp[sq0+3];
    const float q0x=rflf(f0.x), q0y=rflf(f0.y), q0z=rflf(f0.z);
    const float q1x=rflf(f1.x), q1y=rflf(f1.y), q1z=rflf(f1.z);
    const float q2x=rflf(f2.x), q2y=rflf(f2.y), q2z=rflf(f2.z);
    const float q3x=rflf(f3.x), q3y=rflf(f3.y), q3z=rflf(f3.z);
    const float m2x0=-2.f*q0x, m2y0=-2.f*q0y, m2z0=-2.f*q0z;
    const float m2x1=-2.f*q1x, m2y1=-2.f*q1y, m2z1=-2.f*q1z;
    const float m2x2=-2.f*q2x, m2y2=-2.f*q2y, m2z2=-2.f*q2z;
    const float m2x3=-2.f*q3x, m2y3=-2.f*q3y, m2z3=-2.f*q3z;

    const int n0 = __builtin_amdgcn_readfirstlane(gi[sq0+0]);
    const int n1 = __builtin_amdgcn_readfirstlane(gi[sq0+1]);
    const int n2 = __builtin_amdgcn_readfirstlane(gi[sq0+2]);
    const int n3 = __builtin_amdgcn_readfirstlane(gi[sq0+3]);
    const int nn0 = job ? nnidx[b*N_ + n0] : n0;
    const int nn1 = job ? nnidx[b*N_ + n1] : n1;
    const int nn2 = job ? nnidx[b*N_ + n2] : n2;
    const int nn3 = job ? nnidx[b*N_ + n3] : n3;
    const float nx0=rflf(nb[3*nn0+0]), ny0=rflf(nb[3*nn0+1]), nz0=rflf(nb[3*nn0+2]);
    const float nx1=rflf(nb[3*nn1+0]), ny1=rflf(nb[3*nn1+1]), nz1=rflf(nb[3*nn1+2]);
    const float nx2=rflf(nb[3*nn2+0]), ny2=rflf(nb[3*nn2+1]), nz2=rflf(nb[3*nn2+2]);
    const float nx3=rflf(nb[3*nn3+0]), ny3=rflf(nb[3*nn3+1]), nz3=rflf(nb[3*nn3+2]);

    // ---- seed: full bitonic sort of own tile T0 (4 interleaved sorts) ----
    const int j0 = T0*64 + lane;
    float sd0, sd1, sd2, sd3;
    int   si0 = j0, si1 = j0, si2 = j0, si3 = j0;
    {
        float4 p = sp[j0];
        sd0 = fmaf(p.z,m2z0, fmaf(p.y,m2y0, fmaf(p.x,m2x0, p.w)));
        sd1 = fmaf(p.z,m2z1, fmaf(p.y,m2y1, fmaf(p.x,m2x1, p.w)));
        sd2 = fmaf(p.z,m2z2, fmaf(p.y,m2y2, fmaf(p.x,m2x2, p.w)));
        sd3 = fmaf(p.z,m2z3, fmaf(p.y,m2y3, fmaf(p.x,m2x3, p.w)));
        if (lane == sl    ) sd0 = INF;             // exclude self
        if (lane == sl + 1) sd1 = INF;
        if (lane == sl + 2) sd2 = INF;
        if (lane == sl + 3) sd3 = INF;
    }
    #pragma unroll
    for (int k = 2; k <= 64; k <<= 1) {
        #pragma unroll
        for (int jj = k >> 1; jj > 0; jj >>= 1) {
            bool sel = ((lane & k) == 0) == ((lane & jj) == 0);
            { float o=__shfl_xor(sd0,jj); int a=__shfl_xor(si0,jj);
              if ((o<sd0)==sel) { sd0=o; si0=a; } }
            { float o=__shfl_xor(sd1,jj); int a=__shfl_xor(si1,jj);
              if ((o<sd1)==sel) { sd1=o; si1=a; } }
            { float o=__shfl_xor(sd2,jj); int a=__shfl_xor(si2,jj);
              if ((o<sd2)==sel) { sd2=o; si2=a; } }
            { float o=__shfl_xor(sd3,jj); int a=__shfl_xor(si3,jj);
              if ((o<sd3)==sel) { sd3=o; si3=a; } }
        }
    }
    float tau0 = readlane_f(sd0, 15), tau1 = readlane_f(sd1, 15);
    float tau2 = readlane_f(sd2, 15), tau3 = readlane_f(sd3, 15);

    // ---- brute 64-tile scan (skip T0): 1 ds_read_b128 + 3 FMA/query ----
    for (int t = 0; t < NT; ++t) {
        if (t == T0) continue;
        int tb = t*64, j = tb + lane;
        float4 p = sp[j];
        float d0 = fmaf(p.z,m2z0, fmaf(p.y,m2y0, fmaf(p.x,m2x0, p.w)));
        float d1 = fmaf(p.z,m2z1, fmaf(p.y,m2y1, fmaf(p.x,m2x1, p.w)));
        float d2 = fmaf(p.z,m2z2, fmaf(p.y,m2y2, fmaf(p.x,m2x2, p.w)));
        float d3 = fmaf(p.z,m2z3, fmaf(p.y,m2y3, fmaf(p.x,m2x3, p.w)));
        unsigned long long m0 = __ballot(d0 < tau0);
        unsigned long long m1 = __ballot(d1 < tau1);
        unsigned long long m2 = __ballot(d2 < tau2);
        unsigned long long m3 = __ballot(d3 < tau3);
        if (m0 | m1 | m2 | m3) {
            while (m0 | m1 | m2 | m3) {            // 4 independent chains: ILP
                if (m0) POP1(m0, d0, sd0, si0, tb)
                if (m1) POP1(m1, d1, sd1, si1, tb)
                if (m2) POP1(m2, d2, sd2, si2, tb)
                if (m3) POP1(m3, d3, sd3, si3, tb)
            }
            tau0 = readlane_f(sd0, 15); tau1 = readlane_f(sd1, 15);
            tau2 = readlane_f(sd2, 15); tau3 = readlane_f(sd3, 15);
        }
    }

    // ---- kappa = mean_k |dot(normalize(nn - q), normal)| ----
    double ksum = 0.0, kss = 0.0;
#define KTAIL(siN, qxN, qyN, qzN, nxN, nyN, nzN)                           \
    {   float tl = 0.0f;                                                   \
        if (lane < K_) {                                                   \
            float4 p2 = sp[siN];                                           \
            float vx = p2.x - qxN, vy = p2.y - qyN, vz = p2.z - qzN;       \
            float L  = sqrtf(vx*vx + vy*vy + vz*vz) + 1e-12f;              \
            tl = fabsf(fmaf(vz,nzN, fmaf(vy,nyN, vx*nxN))) / L;            \
        }                                                                  \
        tl += __shfl_xor(tl, 1); tl += __shfl_xor(tl, 2);                  \
        tl += __shfl_xor(tl, 4); tl += __shfl_xor(tl, 8);                  \
        if (lane == 0) { double kk = (double)tl * (1.0/16.0);              \
                         ksum += kk; kss += kk*kk; } }
    KTAIL(si0, q0x, q0y, q0z, nx0, ny0, nz0)
    KTAIL(si1, q1x, q1y, q1z, nx1, ny1, nz1)
    KTAIL(si2, q2x, q2y, q2z, nx2, ny2, nz2)
    KTAIL(si3, q3x, q3y, q3z, nx3, ny3, nz3)
#undef KTAIL

    if (lane == 0) { rs[w] = ksum; rss[w] = kss; }
    __syncthreads();
    if (tid == 0) {
        double s = 0.0, ss = 0.0;
        #pragma unroll
        for (int i = 0; i < 16; ++i) { s += rs[i]; ss += rss[i]; }
        int row = job*4 + b;
        atomicAdd(&acc[row*2+0], s);
        atomicAdd(&acc[row*2+1], ss);
    }
}

__global__ void curv_finalize_kernel(const double* __restrict__ acc,
                                     float* __restrict__ out)
{
    if (threadIdx.x == 0 && blockIdx.x == 0) {
        double st[8];
        #pragma unroll
        for (int r = 0; r < 8; ++r) {
            double s   = acc[2*r+0];
            double ss  = acc[2*r+1];
            double var = (ss - s*s / (double)N_) / (double)(N_ - 1);
            st[r] = var > 0.0 ? sqrt(var) : 0.0;
        }
        double o = 0.0;
        #pragma unroll
        for (int bb = 0; bb < 4; ++bb) o += fabs(st[4+bb] - st[bb]);
        out[0] = (float)(o * 0.25);
    }
}

extern "C" void kernel_launch(void* const* d_in, const int* in_sizes, int n_in,
                              void* d_out, int out_size, void* d_ws, size_t ws_size,
                              hipStream_t stream)
{
    const float* ori = (const float*)d_in[0];
    const float* adv = (const float*)d_in[1];
    const float* nrm = (const float*)d_in[2];
    double* acc   = (double*)d_ws;                               // 256 B
    int*    nnidx = (int*)((char*)d_ws + 256);                   // 64 KB
    float4* gs    = (float4*)((char*)d_ws + 256 + 65536);        // 512 KB
    int*    gidx  = (int*)((char*)d_ws + 256 + 65536 + 524288);  // 128 KB
    float*  out   = (float*)d_out;

    hipMemsetAsync(acc, 0, 16 * sizeof(double), stream);
    morton_sort_kernel<<<8, 1024, 0, stream>>>(ori, adv, gs, gidx);
    curv_argmin_kernel<<<B_ * 64, 1024, 0, stream>>>(gs, gidx, nnidx);
    curv_kappa_kernel<<<2 * B_ * 64, 1024, 0, stream>>>(gs, gidx, nrm, nnidx, acc);
    curv_finalize_kernel<<<1, 64, 0, stream>>>(acc, out);
}

// Round 10
// 136.218 us; speedup vs baseline: 1.2313x; 1.2003x over previous
//
#include <hip/hip_runtime.h>
#include <math.h>

#define B_ 4
#define N_ 4096
#define K_ 16
#define NT 64                    // 64 tiles of 64 points per cloud
#define INF __builtin_huge_valf()
#define SLACK 1e-3f              // covers expanded-form fp error in bound test

__device__ __forceinline__ float dpp_shr1_f(float x) {
    return __int_as_float(__builtin_amdgcn_update_dpp(
        __float_as_int(x), __float_as_int(x), 0x111, 0xF, 0xF, false));
}
__device__ __forceinline__ int dpp_shr1_i(int x) {
    return __builtin_amdgcn_update_dpp(x, x, 0x111, 0xF, 0xF, false);
}
__device__ __forceinline__ float readlane_f(float x, int l) {
    return __int_as_float(__builtin_amdgcn_readlane(__float_as_int(x), l));
}
__device__ __forceinline__ float rflf(float x) {   // force to SGPR
    return __int_as_float(__builtin_amdgcn_readfirstlane(__float_as_int(x)));
}
#if __has_builtin(__builtin_amdgcn_inverse_ballot_w64)
#define LANEBIT(m, lane) __builtin_amdgcn_inverse_ballot_w64(m)
#else
#define LANEBIT(m, lane) ((((m) >> (lane)) & 1ull) != 0)
#endif

// pop ONE candidate from mask mi into sorted 16-list (lanes 0..15 asc)
#define POP1(mi, di, sdi, sii, tb)                                         \
    {   int src = __builtin_ctzll(mi); mi &= mi - 1;                       \
        float v = readlane_f(di, src);                                     \
        int  vi = (tb) + src;                                              \
        unsigned long long mg = __ballot(sdi > v);                         \
        float usd = dpp_shr1_f(sdi); int usi = dpp_shr1_i(sii);            \
        bool gt = LANEBIT(mg, lane);                                       \
        bool pg = LANEBIT(mg << 1, lane);                                  \
        sdi = gt ? (pg ? usd : v ) : sdi;                                  \
        sii = gt ? (pg ? usi : vi) : sii; }

__device__ __forceinline__ int spread4(int v) {    // 4 bits -> every 3rd pos
    return (v & 1) | ((v & 2) << 2) | ((v & 4) << 4) | ((v & 8) << 6);
}

__device__ __forceinline__ float aabb2f(float4 lo, float4 hi,
                                        float qx, float qy, float qz) {
    float dx = fmaxf(fmaxf(lo.x - qx, qx - hi.x), 0.f);
    float dy = fmaxf(fmaxf(lo.y - qy, qy - hi.y), 0.f);
    float dz = fmaxf(fmaxf(lo.z - qz, qz - hi.z), 0.f);
    return fmaf(dz, dz, fmaf(dy, dy, dx*dx));
}

// tile-order bitonic sort: MUST tie-break on tile id — AABB keys tie often
// (key 0 for every box containing the query); strict compare drops/dups tiles.
#define TILE_SORT(sk, st)                                                  \
    _Pragma("unroll")                                                      \
    for (int k = 2; k <= 64; k <<= 1) {                                    \
        _Pragma("unroll")                                                  \
        for (int jj = k >> 1; jj > 0; jj >>= 1) {                          \
            bool sel = ((lane & k) == 0) == ((lane & jj) == 0);            \
            float o = __shfl_xor(sk, jj); int a2 = __shfl_xor(st, jj);     \
            bool oless = (o < sk) || (o == sk && a2 < st);                 \
            if (oless == sel) { sk = o; st = a2; }                         \
        }                                                                  \
    }

// -- Morton counting-sort each (set,b) cloud: gs=(x,y,z,|p|^2), gidx=orig ----
__global__ __launch_bounds__(1024) void morton_sort_kernel(
    const float* __restrict__ ori, const float* __restrict__ adv,
    float4* __restrict__ gs, int* __restrict__ gidx)
{
    __shared__ int hist[4096];
    __shared__ int wsum[1024];
    const int tid = threadIdx.x;
    const int set = blockIdx.x >> 2, b = blockIdx.x & 3;
    const float* src = (set ? adv : ori) + (size_t)b * (N_*3);
    float4* dst = gs + (size_t)blockIdx.x * N_;
    int*    dsi = gidx + (size_t)blockIdx.x * N_;

    #pragma unroll
    for (int k = 0; k < 4; ++k) hist[k*1024 + tid] = 0;
    __syncthreads();

    float px[4], py[4], pz[4]; int code[4];
    #pragma unroll
    for (int k = 0; k < 4; ++k) {
        int j = k*1024 + tid;
        float x = src[3*j+0], y = src[3*j+1], z = src[3*j+2];
        px[k] = x; py[k] = y; pz[k] = z;
        int ix = (int)((x + 4.25f) * (16.0f/8.5f));
        int iy = (int)((y + 4.25f) * (16.0f/8.5f));
        int iz = (int)((z + 4.25f) * (16.0f/8.5f));
        ix = ix < 0 ? 0 : (ix > 15 ? 15 : ix);
        iy = iy < 0 ? 0 : (iy > 15 ? 15 : iy);
        iz = iz < 0 ? 0 : (iz > 15 ? 15 : iz);
        code[k] = (spread4(ix) << 2) | (spread4(iy) << 1) | spread4(iz);
        atomicAdd(&hist[code[k]], 1);
    }
    __syncthreads();
    const int h0 = hist[4*tid], h1 = hist[4*tid+1],
              h2 = hist[4*tid+2], h3 = hist[4*tid+3];
    const int s = h0 + h1 + h2 + h3;
    wsum[tid] = s;
    __syncthreads();
    for (int st = 1; st < 1024; st <<= 1) {        // Hillis-Steele inclusive
        int tmp = (tid >= st) ? wsum[tid - st] : 0;
        __syncthreads();
        wsum[tid] += tmp;
        __syncthreads();
    }
    int eb = wsum[tid] - s;                        // exclusive base
    hist[4*tid]   = eb;
    hist[4*tid+1] = eb + h0;
    hist[4*tid+2] = eb + h0 + h1;
    hist[4*tid+3] = eb + h0 + h1 + h2;
    __syncthreads();
    #pragma unroll
    for (int k = 0; k < 4; ++k) {
        int j = k*1024 + tid;
        int pos = atomicAdd(&hist[code[k]], 1);
        float pp = fmaf(pz[k],pz[k], fmaf(py[k],py[k], px[k]*px[k]));
        dst[pos] = make_float4(px[k], py[k], pz[k], pp);
        dsi[pos] = j;
    }
}

// ---- per-tile AABBs of each sorted cloud: ab[cloud*128 + t*2 + {lo,hi}] ----
__global__ __launch_bounds__(1024) void aabb_kernel(
    const float4* __restrict__ gs, float4* __restrict__ ab)
{
    const int tid = threadIdx.x, lane = tid & 63, w = tid >> 6;
    const float4* g = gs + (size_t)blockIdx.x * N_;
    float4* a = ab + (size_t)blockIdx.x * (NT*2);
    #pragma unroll
    for (int i = 0; i < 4; ++i) {
        int t = w*4 + i;
        float4 p = g[t*64 + lane];
        float x0=p.x, x1=p.x, y0=p.y, y1=p.y, z0=p.z, z1=p.z;
        #pragma unroll
        for (int s2 = 1; s2 < 64; s2 <<= 1) {
            x0 = fminf(x0, __shfl_xor(x0, s2)); x1 = fmaxf(x1, __shfl_xor(x1, s2));
            y0 = fminf(y0, __shfl_xor(y0, s2)); y1 = fmaxf(y1, __shfl_xor(y1, s2));
            z0 = fminf(z0, __shfl_xor(z0, s2)); z1 = fmaxf(z1, __shfl_xor(z1, s2));
        }
        if (lane == 0) {
            a[t*2+0] = make_float4(x0, y0, z0, 0.f);
            a[t*2+1] = make_float4(x1, y1, z1, 0.f);
        }
    }
}

// ---------------- argmin(adv -> ori): sorted-order scan w/ early exit --------
__global__ __launch_bounds__(256) void curv_argmin_kernel(
    const float4* __restrict__ gs, const int* __restrict__ gidx,
    const float4* __restrict__ ab, int* __restrict__ nnidx)
{
    const int tid = threadIdx.x, lane = tid & 63;
    const int gw = blockIdx.x*4 + (tid >> 6);      // 0..4095
    const int b  = gw >> 10;
    const int sq0 = (gw & 1023) * 4;
    const float4* go = gs + (size_t)b * N_;
    const int*    io = gidx + (size_t)b * N_;
    const float4* ga = gs + (size_t)(4+b) * N_;
    const int*    ia = gidx + (size_t)(4+b) * N_;
    const float4* abo = ab + (size_t)b * (NT*2);

    float4 f0 = ga[sq0+0], f1 = ga[sq0+1], f2 = ga[sq0+2], f3 = ga[sq0+3];
    const float q0x=rflf(f0.x), q0y=rflf(f0.y), q0z=rflf(f0.z), qq0=rflf(f0.w);
    const float q1x=rflf(f1.x), q1y=rflf(f1.y), q1z=rflf(f1.z), qq1=rflf(f1.w);
    const float q2x=rflf(f2.x), q2y=rflf(f2.y), q2z=rflf(f2.z), qq2=rflf(f2.w);
    const float q3x=rflf(f3.x), q3y=rflf(f3.y), q3z=rflf(f3.z), qq3=rflf(f3.w);
    const float m2x0=-2.f*q0x, m2y0=-2.f*q0y, m2z0=-2.f*q0z;
    const float m2x1=-2.f*q1x, m2y1=-2.f*q1y, m2z1=-2.f*q1z;
    const float m2x2=-2.f*q2x, m2y2=-2.f*q2y, m2z2=-2.f*q2z;
    const float m2x3=-2.f*q3x, m2y3=-2.f*q3y, m2z3=-2.f*q3z;

    float4 lo = abo[lane*2+0], hi = abo[lane*2+1];
    float sk = fminf(fminf(aabb2f(lo,hi,q0x,q0y,q0z), aabb2f(lo,hi,q1x,q1y,q1z)),
                     fminf(aabb2f(lo,hi,q2x,q2y,q2z), aabb2f(lo,hi,q3x,q3y,q3z)));
    int st = lane;
    TILE_SORT(sk, st)

    float dm0=INF,dm1=INF,dm2=INF,dm3=INF; int jm0=0,jm1=0,jm2=0,jm3=0;
    float bound = INF;
    for (int it = 0; it < NT; ++it) {
        float kd = readlane_f(sk, it);
        if (kd >= bound) break;                    // all remaining tiles farther
        int t = __builtin_amdgcn_readlane(st, it);
        int j = t*64 + lane;
        float4 p = go[j];
        float r0 = fmaf(p.z,m2z0, fmaf(p.y,m2y0, fmaf(p.x,m2x0, p.w)));
        float r1 = fmaf(p.z,m2z1, fmaf(p.y,m2y1, fmaf(p.x,m2x1, p.w)));
        float r2 = fmaf(p.z,m2z2, fmaf(p.y,m2y2, fmaf(p.x,m2x2, p.w)));
        float r3 = fmaf(p.z,m2z3, fmaf(p.y,m2y3, fmaf(p.x,m2x3, p.w)));
        if (r0 < dm0) { dm0 = r0; jm0 = j; }       // strict: earliest sorted j
        if (r1 < dm1) { dm1 = r1; jm1 = j; }
        if (r2 < dm2) { dm2 = r2; jm2 = j; }
        if (r3 < dm3) { dm3 = r3; jm3 = j; }
        float g0=dm0, g1=dm1, g2=dm2, g3=dm3;      // wave-min -> uniform bound
        #pragma unroll
        for (int s2 = 1; s2 < 64; s2 <<= 1) {
            g0 = fminf(g0, __shfl_xor(g0, s2));
            g1 = fminf(g1, __shfl_xor(g1, s2));
            g2 = fminf(g2, __shfl_xor(g2, s2));
            g3 = fminf(g3, __shfl_xor(g3, s2));
        }
        bound = fmaxf(fmaxf(g0+qq0, g1+qq1), fmaxf(g2+qq2, g3+qq3)) + SLACK;
    }
    #pragma unroll
    for (int s2 = 1; s2 < 64; s2 <<= 1) {          // final lex (r, idx) min
        { float od=__shfl_xor(dm0,s2); int oj=__shfl_xor(jm0,s2);
          if (od<dm0 || (od==dm0 && oj<jm0)) { dm0=od; jm0=oj; } }
        { float od=__shfl_xor(dm1,s2); int oj=__shfl_xor(jm1,s2);
          if (od<dm1 || (od==dm1 && oj<jm1)) { dm1=od; jm1=oj; } }
        { float od=__shfl_xor(dm2,s2); int oj=__shfl_xor(jm2,s2);
          if (od<dm2 || (od==dm2 && oj<jm2)) { dm2=od; jm2=oj; } }
        { float od=__shfl_xor(dm3,s2); int oj=__shfl_xor(jm3,s2);
          if (od<dm3 || (od==dm3 && oj<jm3)) { dm3=od; jm3=oj; } }
    }
    if (lane == 0) {
        nnidx[b*N_ + ia[sq0+0]] = io[jm0];
        nnidx[b*N_ + ia[sq0+1]] = io[jm1];
        nnidx[b*N_ + ia[sq0+2]] = io[jm2];
        nnidx[b*N_ + ia[sq0+3]] = io[jm3];
    }
}

// ---------------- kappa for both sets, accumulate (sum, sumsq) ---------------
__global__ __launch_bounds__(256) void curv_kappa_kernel(
    const float4* __restrict__ gs, const int* __restrict__ gidx,
    const float4* __restrict__ ab, const float* __restrict__ nrm,
    const int* __restrict__ nnidx, double* __restrict__ acc)
{
    __shared__ double rs[4], rss[4];
    const int tid = threadIdx.x, lane = tid & 63, w = tid >> 6;
    const int gw = blockIdx.x*4 + w;               // 0..8191
    const int job = gw >> 12;
    const int b   = (gw >> 10) & 3;
    const int sq0 = (gw & 1023) * 4;
    const float4* g  = gs + (size_t)(job*4+b) * N_;
    const int*    gi = gidx + (size_t)(job*4+b) * N_;
    const float4* abo = ab + (size_t)(job*4+b) * (NT*2);
    const float*  nb = nrm + (size_t)b * (N_*3);

    const int T0 = sq0 >> 6, sl = sq0 & 63;
    float4 f0 = g[sq0+0], f1 = g[sq0+1], f2 = g[sq0+2], f3 = g[sq0+3];
    const float q0x=rflf(f0.x), q0y=rflf(f0.y), q0z=rflf(f0.z), qq0=rflf(f0.w);
    const float q1x=rflf(f1.x), q1y=rflf(f1.y), q1z=rflf(f1.z), qq1=rflf(f1.w);
    const float q2x=rflf(f2.x), q2y=rflf(f2.y), q2z=rflf(f2.z), qq2=rflf(f2.w);
    const float q3x=rflf(f3.x), q3y=rflf(f3.y), q3z=rflf(f3.z), qq3=rflf(f3.w);
    const float m2x0=-2.f*q0x, m2y0=-2.f*q0y, m2z0=-2.f*q0z;
    const float m2x1=-2.f*q1x, m2y1=-2.f*q1y, m2z1=-2.f*q1z;
    const float m2x2=-2.f*q2x, m2y2=-2.f*q2y, m2z2=-2.f*q2z;
    const float m2x3=-2.f*q3x, m2y3=-2.f*q3y, m2z3=-2.f*q3z;

    const int n0 = __builtin_amdgcn_readfirstlane(gi[sq0+0]);
    const int n1 = __builtin_amdgcn_readfirstlane(gi[sq0+1]);
    const int n2 = __builtin_amdgcn_readfirstlane(gi[sq0+2]);
    const int n3 = __builtin_amdgcn_readfirstlane(gi[sq0+3]);
    const int nn0 = job ? nnidx[b*N_ + n0] : n0;
    const int nn1 = job ? nnidx[b*N_ + n1] : n1;
    const int nn2 = job ? nnidx[b*N_ + n2] : n2;
    const int nn3 = job ? nnidx[b*N_ + n3] : n3;
    const float nx0=rflf(nb[3*nn0+0]), ny0=rflf(nb[3*nn0+1]), nz0=rflf(nb[3*nn0+2]);
    const float nx1=rflf(nb[3*nn1+0]), ny1=rflf(nb[3*nn1+1]), nz1=rflf(nb[3*nn1+2]);
    const float nx2=rflf(nb[3*nn2+0]), ny2=rflf(nb[3*nn2+1]), nz2=rflf(nb[3*nn2+2]);
    const float nx3=rflf(nb[3*nn3+0]), ny3=rflf(nb[3*nn3+1]), nz3=rflf(nb[3*nn3+2]);

    float4 lo = abo[lane*2+0], hi = abo[lane*2+1];
    float sk = fminf(fminf(aabb2f(lo,hi,q0x,q0y,q0z), aabb2f(lo,hi,q1x,q1y,q1z)),
                     fminf(aabb2f(lo,hi,q2x,q2y,q2z), aabb2f(lo,hi,q3x,q3y,q3z)));
    int st = lane;
    TILE_SORT(sk, st)

    // ---- seed: full bitonic sort of own tile T0 (4 interleaved sorts) ----
    const int j0 = T0*64 + lane;
    float sd0, sd1, sd2, sd3;
    int   si0 = j0, si1 = j0, si2 = j0, si3 = j0;
    {
        float4 p = g[j0];
        sd0 = fmaf(p.z,m2z0, fmaf(p.y,m2y0, fmaf(p.x,m2x0, p.w)));
        sd1 = fmaf(p.z,m2z1, fmaf(p.y,m2y1, fmaf(p.x,m2x1, p.w)));
        sd2 = fmaf(p.z,m2z2, fmaf(p.y,m2y2, fmaf(p.x,m2x2, p.w)));
        sd3 = fmaf(p.z,m2z3, fmaf(p.y,m2y3, fmaf(p.x,m2x3, p.w)));
        if (lane == sl    ) sd0 = INF;             // exclude self
        if (lane == sl + 1) sd1 = INF;
        if (lane == sl + 2) sd2 = INF;
        if (lane == sl + 3) sd3 = INF;
    }
    #pragma unroll
    for (int k = 2; k <= 64; k <<= 1) {
        #pragma unroll
        for (int jj = k >> 1; jj > 0; jj >>= 1) {
            bool sel = ((lane & k) == 0) == ((lane & jj) == 0);
            { float o=__shfl_xor(sd0,jj); int a=__shfl_xor(si0,jj);
              if ((o<sd0)==sel) { sd0=o; si0=a; } }
            { float o=__shfl_xor(sd1,jj); int a=__shfl_xor(si1,jj);
              if ((o<sd1)==sel) { sd1=o; si1=a; } }
            { float o=__shfl_xor(sd2,jj); int a=__shfl_xor(si2,jj);
              if ((o<sd2)==sel) { sd2=o; si2=a; } }
            { float o=__shfl_xor(sd3,jj); int a=__shfl_xor(si3,jj);
              if ((o<sd3)==sel) { sd3=o; si3=a; } }
        }
    }
    float tau0 = readlane_f(sd0, 15), tau1 = readlane_f(sd1, 15);
    float tau2 = readlane_f(sd2, 15), tau3 = readlane_f(sd3, 15);
    float bound = fmaxf(fmaxf(tau0+qq0, tau1+qq1),
                        fmaxf(tau2+qq2, tau3+qq3)) + SLACK;

    // ---- sorted-order tile scan with early exit ----
    for (int it = 0; it < NT; ++it) {
        float kd = readlane_f(sk, it);
        if (kd >= bound) break;
        int t = __builtin_amdgcn_readlane(st, it);
        if (t == T0) continue;
        int tb = t*64, j = tb + lane;
        float4 p = g[j];
        float d0 = fmaf(p.z,m2z0, fmaf(p.y,m2y0, fmaf(p.x,m2x0, p.w)));
        float d1 = fmaf(p.z,m2z1, fmaf(p.y,m2y1, fmaf(p.x,m2x1, p.w)));
        float d2 = fmaf(p.z,m2z2, fmaf(p.y,m2y2, fmaf(p.x,m2x2, p.w)));
        float d3 = fmaf(p.z,m2z3, fmaf(p.y,m2y3, fmaf(p.x,m2x3, p.w)));
        unsigned long long m0 = __ballot(d0 < tau0);
        unsigned long long m1 = __ballot(d1 < tau1);
        unsigned long long m2 = __ballot(d2 < tau2);
        unsigned long long m3 = __ballot(d3 < tau3);
        if (m0 | m1 | m2 | m3) {
            while (m0 | m1 | m2 | m3) {            // 4 independent chains: ILP
                if (m0) POP1(m0, d0, sd0, si0, tb)
                if (m1) POP1(m1, d1, sd1, si1, tb)
                if (m2) POP1(m2, d2, sd2, si2, tb)
                if (m3) POP1(m3, d3, sd3, si3, tb)
            }
            tau0 = readlane_f(sd0, 15); tau1 = readlane_f(sd1, 15);
            tau2 = readlane_f(sd2, 15); tau3 = readlane_f(sd3, 15);
            bound = fmaxf(fmaxf(tau0+qq0, tau1+qq1),
                          fmaxf(tau2+qq2, tau3+qq3)) + SLACK;
        }
    }

    // ---- kappa = mean_k |dot(normalize(nn - q), normal)| ----
    double ksum = 0.0, kss = 0.0;
#define KTAIL(siN, qxN, qyN, qzN, nxN, nyN, nzN)                           \
    {   float tl = 0.0f;                                                   \
        if (lane < K_) {                                                   \
            float4 p2 = g[siN];                                            \
            float vx = p2.x - qxN, vy = p2.y - qyN, vz = p2.z - qzN;       \
            float L  = sqrtf(vx*vx + vy*vy + vz*vz) + 1e-12f;              \
            tl = fabsf(fmaf(vz,nzN, fmaf(vy,nyN, vx*nxN))) / L;            \
        }                                                                  \
        tl += __shfl_xor(tl, 1); tl += __shfl_xor(tl, 2);                  \
        tl += __shfl_xor(tl, 4); tl += __shfl_xor(tl, 8);                  \
        if (lane == 0) { double kk = (double)tl * (1.0/16.0);              \
                         ksum += kk; kss += kk*kk; } }
    KTAIL(si0, q0x, q0y, q0z, nx0, ny0, nz0)
    KTAIL(si1, q1x, q1y, q1z, nx1, ny1, nz1)
    KTAIL(si2, q2x, q2y, q2z, nx2, ny2, nz2)
    KTAIL(si3, q3x, q3y, q3z, nx3, ny3, nz3)
#undef KTAIL

    if (lane == 0) { rs[w] = ksum; rss[w] = kss; }
    __syncthreads();
    if (tid == 0) {
        double s  = rs[0] + rs[1] + rs[2] + rs[3];
        double ss = rss[0] + rss[1] + rss[2] + rss[3];
        int row = job*4 + b;
        atomicAdd(&acc[row*2+0], s);
        atomicAdd(&acc[row*2+1], ss);
    }
}

__global__ void curv_finalize_kernel(const double* __restrict__ acc,
                                     float* __restrict__ out)
{
    if (threadIdx.x == 0 && blockIdx.x == 0) {
        double st[8];
        #pragma unroll
        for (int r = 0; r < 8; ++r) {
            double s   = acc[2*r+0];
            double ss  = acc[2*r+1];
            double var = (ss - s*s / (double)N_) / (double)(N_ - 1);
            st[r] = var > 0.0 ? sqrt(var) : 0.0;
        }
        double o = 0.0;
        #pragma unroll
        for (int bb = 0; bb < 4; ++bb) o += fabs(st[4+bb] - st[bb]);
        out[0] = (float)(o * 0.25);
    }
}

extern "C" void kernel_launch(void* const* d_in, const int* in_sizes, int n_in,
                              void* d_out, int out_size, void* d_ws, size_t ws_size,
                              hipStream_t stream)
{
    const float* ori = (const float*)d_in[0];
    const float* adv = (const float*)d_in[1];
    const float* nrm = (const float*)d_in[2];
    double* acc   = (double*)d_ws;                               // 256 B
    int*    nnidx = (int*)((char*)d_ws + 256);                   // 64 KB
    float4* gs    = (float4*)((char*)d_ws + 256 + 65536);        // 512 KB
    int*    gidx  = (int*)((char*)d_ws + 256 + 65536 + 524288);  // 128 KB
    float4* ab    = (float4*)((char*)d_ws + 256 + 65536 + 524288 + 131072); // 16 KB
    float*  out   = (float*)d_out;

    hipMemsetAsync(acc, 0, 16 * sizeof(double), stream);
    morton_sort_kernel<<<8, 1024, 0, stream>>>(ori, adv, gs, gidx);
    aabb_kernel<<<8, 1024, 0, stream>>>(gs, ab);
    curv_argmin_kernel<<<1024, 256, 0, stream>>>(gs, gidx, ab, nnidx);
    curv_kappa_kernel<<<2048, 256, 0, stream>>>(gs, gidx, ab, nrm, nnidx, acc);
    curv_finalize_kernel<<<1, 64, 0, stream>>>(acc, out);
}